// Round 1
// baseline (356.953 us; speedup 1.0000x reference)
//
#include <hip/hip_runtime.h>
#include <math.h>

// Problem constants (from reference): B=64, N=64, D=6, L=32, T=2048
#define TB 2048
#define LL 32
#define NP 64
#define DD 6
#define BB 64
#define NLANES 8      // lanes per DP problem (anti-diagonal wavefront width)
#define ROWS 4        // pattern rows per lane (L = NLANES*ROWS = 32)
#define PAD 8         // LDS pad each side (>= NLANES-1, float4-aligned)

// Recurrence (from reference):
//   D[0, j] = c[0, j]
//   D[i, j] = c[i, j] + w * min(D[i-1, j], D[i, j-1], D[i-1, j-1])
//   out[b,n,d,j] = sqrt(D[L-1, j])
//
// Skewed wavefront: lane k computes column j = s - k (rows 4k..4k+3) at step s.
// up (D[4k-1, j])   = lane k-1's row-3 value from step s-1  -> __shfl_up(cur3)
// diag (D[4k-1,j-1]) = lane k-1's row-3 value from step s-2 -> previous step's up
// Invalid columns (j<0 or j>=T) carry +inf, which propagates harmlessly
// (fminf(inf,x)=x, w*inf+c=inf); only prologue/epilogue need the check.

template<bool CHECK>
__device__ __forceinline__ void dtw_step(
    int s, int k, bool k0, bool k7,
    const float* __restrict__ xp, float w,
    float p0, float p1, float p2, float p3,
    float& cur0, float& cur1, float& cur2, float& cur3,
    float& diag, float* __restrict__ orow)
{
    const float INF = __builtin_inff();
    float up = __shfl_up(cur3, 1, 64);   // lane k-1 row3, step s-1 => D[4k-1, s-k]
    float xv = xp[s];                    // xs[PAD + s - k]
    int j = s - k;
    bool valid = true;
    if (CHECK) valid = ((unsigned)j < (unsigned)TB);

    float c0 = p0 - xv; c0 *= c0;
    float c1 = p1 - xv; c1 *= c1;
    float c2 = p2 - xv; c2 *= c2;
    float c3 = p3 - xv; c3 *= c3;

    // row 4k
    float m0 = fminf(fminf(cur0, up), diag);
    float v0 = k0 ? c0 : fmaf(w, m0, c0);      // global row 0 has free start
    float n0 = (CHECK && !valid) ? INF : v0;
    // row 4k+1
    float m1 = fminf(fminf(cur1, n0), cur0);
    float v1 = fmaf(w, m1, c1);
    float n1 = (CHECK && !valid) ? INF : v1;
    // row 4k+2
    float m2 = fminf(fminf(cur2, n1), cur1);
    float v2 = fmaf(w, m2, c2);
    float n2 = (CHECK && !valid) ? INF : v2;
    // row 4k+3
    float m3 = fminf(fminf(cur3, n2), cur2);
    float v3 = fmaf(w, m3, c3);
    float n3 = (CHECK && !valid) ? INF : v3;

    diag = up;
    cur0 = n0; cur1 = n1; cur2 = n2; cur3 = n3;

    if (k7) {                                  // global row L-1
        if (!CHECK || valid) orow[j] = sqrtf(n3);
    }
}

__global__ __launch_bounds__(256) void dtw_kernel(
    const float* __restrict__ x,      // (B, D, T)
    const float* __restrict__ patts,  // (N, L)
    const float* __restrict__ wptr,   // scalar
    float* __restrict__ out)          // (B, N, D, T)
{
    __shared__ float xs[PAD + TB + PAD];

    const int bid  = blockIdx.x;      // B*D*2 blocks
    const int half = bid & 1;         // which 32 of the 64 patterns
    const int bd   = bid >> 1;        // b*D + d
    const int b    = bd / DD;
    const int d    = bd - b * DD;
    const int tid  = threadIdx.x;

    // Stage x[b,d,:] (8 KB) into LDS, shared by all 32 pattern-groups.
    const float4* xrow = (const float4*)(x + (size_t)bd * TB);
    float4* xs4 = (float4*)(xs + PAD);
    xs4[tid]       = xrow[tid];
    xs4[tid + 256] = xrow[tid + 256];
    if (tid < PAD) { xs[tid] = 0.f; xs[PAD + TB + tid] = 0.f; }
    __syncthreads();

    const int g = tid >> 3;           // group 0..31 (one pattern each)
    const int k = tid & 7;            // lane within group
    const int n = half * 32 + g;

    const float w = wptr[0];
    const float4 pv = *(const float4*)(patts + n * LL + k * ROWS);
    const float p0 = pv.x, p1 = pv.y, p2 = pv.z, p3 = pv.w;

    float* orow = out + (((size_t)b * NP + n) * DD + d) * TB;
    const float* xp = xs + PAD - k;

    const float INF = __builtin_inff();
    float cur0 = INF, cur1 = INF, cur2 = INF, cur3 = INF, diag = INF;
    const bool k0 = (k == 0), k7 = (k == NLANES - 1);

    int s = 0;
    // prologue: ramp-in, some lanes have j < 0
    for (; s < NLANES - 1; ++s)
        dtw_step<true>(s, k, k0, k7, xp, w, p0, p1, p2, p3,
                       cur0, cur1, cur2, cur3, diag, orow);
    // steady state: all lanes valid, no boundary checks
    #pragma unroll 4
    for (; s < TB; ++s)
        dtw_step<false>(s, k, k0, k7, xp, w, p0, p1, p2, p3,
                        cur0, cur1, cur2, cur3, diag, orow);
    // epilogue: ramp-out, some lanes have j >= T
    for (; s < TB + NLANES - 1; ++s)
        dtw_step<true>(s, k, k0, k7, xp, w, p0, p1, p2, p3,
                       cur0, cur1, cur2, cur3, diag, orow);
}

extern "C" void kernel_launch(void* const* d_in, const int* in_sizes, int n_in,
                              void* d_out, int out_size, void* d_ws, size_t ws_size,
                              hipStream_t stream) {
    const float* x     = (const float*)d_in[0];
    const float* patts = (const float*)d_in[1];
    const float* wptr  = (const float*)d_in[2];
    float* out = (float*)d_out;

    dim3 grid(BB * DD * 2);   // 768 blocks: one (b,d) row per pair of blocks
    dim3 block(256);          // 32 pattern-groups of 8 lanes
    dtw_kernel<<<grid, block, 0, stream>>>(x, patts, wptr, out);
}

// Round 2
// 304.591 us; speedup vs baseline: 1.1719x; 1.1719x over previous
//
#include <hip/hip_runtime.h>
#include <math.h>

// Problem constants: B=64, N=64, D=6, L=32, T=2048
#define TB 2048
#define LL 32
#define NP 64
#define DD 6
#define BB 64
#define NLANES 8      // lanes per DP problem
#define ROWS 4        // pattern rows per lane (L = 8*4 = 32)
#define CW 16         // columns per macro-step (tile width)
#define MSTEPS (TB/CW)  // 128

// Recurrence:
//   D[0, j] = c[0, j]
//   D[i, j] = c[i, j] + w * min(D[i-1, j], D[i, j-1], D[i-1, j-1])
//   out[b,n,d,j] = sqrt(D[L-1, j])
//
// Blocked wavefront: lane k owns rows 4k..4k+3. At macro-step m it processes
// column block q = m-k (16 columns). Lane k-1 finished block q at step m-1,
// so its row-3 values for those 16 columns arrive via a BATCH of 16
// independent __shfl_up's (one lgkmcnt wait per 64 cells, not per 4).
// diag for the tile's first column = last received value of the previous
// macro-step (diagC). Left boundary = lane's own a0..a3 carried in registers.
// Ramp in/out: INF propagates harmlessly (no 0*INF anywhere; w finite);
// ramp-out garbage is finite and never reaches a valid lane's inputs.

__global__ __launch_bounds__(256) void dtw_kernel(
    const float* __restrict__ x,      // (B, D, T)
    const float* __restrict__ patts,  // (N, L)
    const float* __restrict__ wptr,   // scalar
    float* __restrict__ out)          // (B, N, D, T)
{
    __shared__ float xs[TB];

    const int bid  = blockIdx.x;      // B*D*2 blocks
    const int half = bid & 1;         // which 32 of the 64 patterns
    const int bd   = bid >> 1;        // b*D + d
    const int tid  = threadIdx.x;

    // Stage x[b,d,:] (8 KB) into LDS, shared by all 32 pattern-groups.
    const float4* xrow = (const float4*)(x + (size_t)bd * TB);
    float4* xs4 = (float4*)xs;
    xs4[tid]       = xrow[tid];
    xs4[tid + 256] = xrow[tid + 256];
    __syncthreads();

    const int g = tid >> 3;           // group 0..31 (one pattern each)
    const int k = tid & 7;            // lane within group
    const int n = half * 32 + g;

    const float w = wptr[0];
    const float4 pv = *(const float4*)(patts + n * LL + k * ROWS);
    const float p0 = pv.x, p1 = pv.y, p2 = pv.z, p3 = pv.w;

    const int b = bd / DD, d = bd - (bd / DD) * DD;
    float* __restrict__ orow = out + (((size_t)b * NP + n) * DD + d) * TB;

    const bool k0 = (k == 0), k7 = (k == NLANES - 1);
    const float INF = __builtin_inff();

    float a0 = INF, a1 = INF, a2 = INF, a3 = INF;   // current/left column
    float diagC = INF;                              // diag for tile col 0
    float r3[CW];                                   // own row-3 values of last block
    #pragma unroll
    for (int c = 0; c < CW; ++c) r3[c] = INF;

    for (int m = 0; m < MSTEPS + NLANES - 1; ++m) {
        const int q = m - k;
        const bool valid = ((unsigned)q < (unsigned)MSTEPS);

        // Batch-shuffle lane k-1's row-3 values for block q (16 independent
        // ds_bpermutes, latency fully overlapped).
        float recv[CW];
        #pragma unroll
        for (int c = 0; c < CW; ++c) recv[c] = __shfl_up(r3[c], 1, 64);

        // x values for this tile (clamped for ramp steps; results unused then).
        const int qq = valid ? q : 0;
        const float4* xq = (const float4*)(xs + qq * CW);
        const float4 xA = xq[0], xB = xq[1], xC = xq[2], xD = xq[3];
        const float xv[CW] = {xA.x, xA.y, xA.z, xA.w,  xB.x, xB.y, xB.z, xB.w,
                              xC.x, xC.y, xC.z, xC.w,  xD.x, xD.y, xD.z, xD.w};

        float diag = diagC;
        #pragma unroll
        for (int c = 0; c < CW; ++c) {
            const float xvc = xv[c];
            float t0 = p0 - xvc, t1 = p1 - xvc, t2 = p2 - xvc, t3 = p3 - xvc;
            const float c0 = t0 * t0, c1 = t1 * t1, c2 = t2 * t2, c3 = t3 * t3;
            const float up = recv[c];
            const float l0 = a0, l1 = a1, l2 = a2, l3 = a3;

            const float m0 = fminf(fminf(l0, up), diag);   // v_min3
            const float v0 = k0 ? c0 : fmaf(w, m0, c0);    // global row 0: free start
            const float m1 = fminf(fminf(l1, v0), l0);
            const float v1 = fmaf(w, m1, c1);
            const float m2 = fminf(fminf(l2, v1), l1);
            const float v2 = fmaf(w, m2, c2);
            const float m3 = fminf(fminf(l3, v2), l2);
            const float v3 = fmaf(w, m3, c3);

            a0 = v0; a1 = v1; a2 = v2; a3 = v3;
            diag = up;
            r3[c] = v3;
        }
        diagC = diag;   // == recv[CW-1]

        // Row L-1 output: 64 B contiguous per macro-step (coalesced float4s).
        if (k7 && valid) {
            float4* op = (float4*)(orow + q * CW);
            op[0] = make_float4(sqrtf(r3[0]),  sqrtf(r3[1]),  sqrtf(r3[2]),  sqrtf(r3[3]));
            op[1] = make_float4(sqrtf(r3[4]),  sqrtf(r3[5]),  sqrtf(r3[6]),  sqrtf(r3[7]));
            op[2] = make_float4(sqrtf(r3[8]),  sqrtf(r3[9]),  sqrtf(r3[10]), sqrtf(r3[11]));
            op[3] = make_float4(sqrtf(r3[12]), sqrtf(r3[13]), sqrtf(r3[14]), sqrtf(r3[15]));
        }
    }
}

extern "C" void kernel_launch(void* const* d_in, const int* in_sizes, int n_in,
                              void* d_out, int out_size, void* d_ws, size_t ws_size,
                              hipStream_t stream) {
    const float* x     = (const float*)d_in[0];
    const float* patts = (const float*)d_in[1];
    const float* wptr  = (const float*)d_in[2];
    float* out = (float*)d_out;

    dim3 grid(BB * DD * 2);   // 768 blocks: one (b,d) per pair of blocks
    dim3 block(256);          // 32 pattern-groups of 8 lanes
    dtw_kernel<<<grid, block, 0, stream>>>(x, patts, wptr, out);
}